// Round 13
// baseline (251.002 us; speedup 1.0000x reference)
//
#include <hip/hip_runtime.h>
#include <hip/hip_bf16.h>
#include <math.h>

#define L_SEQ 2048
#define NB 4
#define DMODEL 256
#define NH 8
#define DHEAD 32
#define NROW (NB*L_SEQ)

typedef __attribute__((ext_vector_type(8))) short short8;
typedef __attribute__((ext_vector_type(4))) float f32x4;

__device__ __forceinline__ float bf2f(short v) {
    union { unsigned u; float f; } x; x.u = ((unsigned)(unsigned short)v) << 16; return x.f;
}
__device__ __forceinline__ short f2bf(float f) {
    union { float f; unsigned u; } x; x.f = f;
    unsigned r = x.u + 0x7fff + ((x.u >> 16) & 1);
    return (short)(r >> 16);
}
__device__ __forceinline__ short8 zero8() {
    short8 z;
    #pragma unroll
    for (int i = 0; i < 8; ++i) z[i] = 0;
    return z;
}

// ---------------- fused prep: layernorm (blocks 0..2047) + PE (2048..3071) + wcvt (3072..3151) ----------------
__global__ __launch_bounds__(256)
void prep_kernel(const float* __restrict__ x, const float* __restrict__ gamma,
                 const float* __restrict__ beta, short* __restrict__ xnb,
                 short* __restrict__ peb,
                 const float* __restrict__ W0, const float* __restrict__ W1,
                 const float* __restrict__ W2, const float* __restrict__ W3,
                 const float* __restrict__ W4, short* __restrict__ WT) {
    const int bid = blockIdx.x;
    __shared__ float s[64][65];
    if (bid < 2048) {
        int lane = threadIdx.x & 63;
        int row  = bid*4 + (threadIdx.x >> 6);
        const float4 a = *(const float4*)(x + (size_t)row*DMODEL + lane*4);
        float sm  = a.x+a.y+a.z+a.w;
        float s2 = a.x*a.x+a.y*a.y+a.z*a.z+a.w*a.w;
        #pragma unroll
        for (int o = 32; o; o >>= 1) { sm += __shfl_xor(sm,o); s2 += __shfl_xor(s2,o); }
        float mu  = sm * (1.f/DMODEL);
        float var = s2 * (1.f/DMODEL) - mu*mu;
        float rst = rsqrtf(var + 1e-3f);
        const float4 g  = *(const float4*)(gamma + lane*4);
        const float4 bt = *(const float4*)(beta  + lane*4);
        short4 o;
        o.x = f2bf((a.x-mu)*rst*g.x + bt.x);
        o.y = f2bf((a.y-mu)*rst*g.y + bt.y);
        o.z = f2bf((a.z-mu)*rst*g.z + bt.z);
        o.w = f2bf((a.w-mu)*rst*g.w + bt.w);
        *(short4*)(xnb + (size_t)row*DMODEL + lane*4) = o;
    } else if (bid < 3072) {
        int idx = (bid-2048)*256 + threadIdx.x;
        int l = idx >> 7, m = idx & 127;
        double ang = (double)l * exp((double)m * (-9.210340371976184/128.0));
        unsigned sv = (unsigned)(unsigned short)f2bf((float)sin(ang));
        unsigned cv = (unsigned)(unsigned short)f2bf((float)cos(ang));
        *(unsigned*)(peb + l*DMODEL + 2*m) = sv | (cv << 16);
    } else {
        const int r  = bid - 3072;           // 0..79
        const int z  = r >> 4, rr = r & 15;
        const float* W = (z==0)?W0:(z==1)?W1:(z==2)?W2:(z==3)?W3:W4;
        short* O = WT + (size_t)z*65536;
        const int k0 = (rr >> 2)*64, n0 = (rr & 3)*64;
        const int c = threadIdx.x & 63, r4 = threadIdx.x >> 6;
        #pragma unroll
        for (int i = 0; i < 16; ++i) {
            int rw = r4 + 4*i;
            s[c][rw] = W[(size_t)(k0+rw)*256 + n0 + c];
        }
        __syncthreads();
        #pragma unroll
        for (int i = 0; i < 16; ++i) {
            int rn = r4 + 4*i;
            O[(size_t)(n0+rn)*256 + k0 + c] = f2bf(s[rn][c]);
        }
    }
}

// ---------------- bf16 MFMA projections: C = A @ W (+bias) ----------------
// z==2 (V projection) writes DIRECTLY to vT[b,h,d,l].
__global__ __launch_bounds__(256, 2)
void projmm_kernel(const short* __restrict__ xnb, const short* __restrict__ peb,
                   const short* __restrict__ WT,
                   const float* __restrict__ bq, const float* __restrict__ bk,
                   const float* __restrict__ bv,
                   short* __restrict__ q, short* __restrict__ kb,
                   short* __restrict__ vT, short* __restrict__ pbuf) {
    const int bid = blockIdx.x;
    int z, rb;
    if (bid < 384) { z = bid >> 7; rb = bid & 127; }
    else           { z = 3;        rb = bid - 384; }
    const short* A = (z == 3) ? peb : xnb;
    const short* W = WT + (size_t)z*65536;
    const int t = threadIdx.x;
    const int w = t >> 6, l = t & 63, lc = l & 15, lg = l >> 4;
    const int m0 = rb*64 + 16*w;

    short8 afr[8];
    #pragma unroll
    for (int ks = 0; ks < 8; ++ks)
        afr[ks] = *(const short8*)(A + (size_t)(m0+lc)*256 + ks*32 + lg*8);

    const f32x4 zf = {0.f,0.f,0.f,0.f};
    f32x4 acc[16];
    #pragma unroll
    for (int ct = 0; ct < 16; ++ct) acc[ct] = zf;

    #pragma unroll
    for (int ct = 0; ct < 16; ++ct) {
        #pragma unroll
        for (int ks = 0; ks < 8; ++ks) {
            const short8 bfr = *(const short8*)(W + (size_t)(ct*16+lc)*256 + ks*32 + lg*8);
            acc[ct] = __builtin_amdgcn_mfma_f32_16x16x32_bf16(afr[ks], bfr, acc[ct], 0, 0, 0);
        }
    }

    if (z == 2) {
        const int bb = m0 >> 11;
        const int l0 = (m0 & 2047) + 4*lg;
        #pragma unroll
        for (int ct = 0; ct < 16; ++ct) {
            const int cc = ct*16 + lc;
            const float bias = bv[cc];
            const int hh = cc >> 5, dd = cc & 31;
            short4 o;
            o.x = f2bf(acc[ct][0] + bias);
            o.y = f2bf(acc[ct][1] + bias);
            o.z = f2bf(acc[ct][2] + bias);
            o.w = f2bf(acc[ct][3] + bias);
            *(short4*)(vT + ((size_t)((bb*NH + hh)*DHEAD + dd))*L_SEQ + l0) = o;
        }
    } else {
        #pragma unroll
        for (int ct = 0; ct < 16; ++ct) {
            const int cc = ct*16 + lc;
            float bias = 0.f;
            if (z == 0) bias = bq[cc];
            else if (z == 1) bias = bk[cc];
            #pragma unroll
            for (int r = 0; r < 4; ++r) {
                const size_t idx = (size_t)(m0 + 4*lg + r)*DMODEL + cc;
                const short v = f2bf(acc[ct][r] + bias);
                if (z == 0)      q[idx]    = v;
                else if (z == 1) kb[idx]   = v;
                else             pbuf[idx] = v;
            }
        }
    }
}

// ---------------- bf16 MFMA out-projection: out = ctxb @ Wo + bo (f32 out) ----------------
__global__ __launch_bounds__(256, 2)
void outmm_kernel(const short* __restrict__ ctxb, const short* __restrict__ WTo,
                  const float* __restrict__ bo, float* __restrict__ out) {
    const int rb = blockIdx.x;
    const int t = threadIdx.x;
    const int w = t >> 6, l = t & 63, lc = l & 15, lg = l >> 4;
    const int m0 = rb*64 + 16*w;

    short8 afr[8];
    #pragma unroll
    for (int ks = 0; ks < 8; ++ks)
        afr[ks] = *(const short8*)(ctxb + (size_t)(m0+lc)*256 + ks*32 + lg*8);

    const f32x4 zf = {0.f,0.f,0.f,0.f};
    f32x4 acc[16];
    #pragma unroll
    for (int ct = 0; ct < 16; ++ct) acc[ct] = zf;

    #pragma unroll
    for (int ct = 0; ct < 16; ++ct) {
        #pragma unroll
        for (int ks = 0; ks < 8; ++ks) {
            const short8 bfr = *(const short8*)(WTo + (size_t)(ct*16+lc)*256 + ks*32 + lg*8);
            acc[ct] = __builtin_amdgcn_mfma_f32_16x16x32_bf16(afr[ks], bfr, acc[ct], 0, 0, 0);
        }
    }

    #pragma unroll
    for (int ct = 0; ct < 16; ++ct) {
        const int cc = ct*16 + lc;
        const float bias = bo[cc];
        #pragma unroll
        for (int r = 0; r < 4; ++r)
            out[(size_t)(m0 + 4*lg + r)*DMODEL + cc] = acc[ct][r] + bias;
    }
}

// ---------------- fused MFMA attention: KBLK=128 (2 k-tiles/iteration), barrier-free ----------------
// R12 null => limiter is the NUMBER of serial chain iterations (fence->gather->softmax->pack),
// invariant at 32 since R4. This round halves it: 16 iterations of 128 keys. Per iteration:
// 8 content MFMA, 9 pos MFMA (3-path on the PAIR; 18 on <=2 crossing pairs), ONE lgkmcnt(0),
// deferred PV of previous pair (8 MFMA), 32-element gather, ONE tree-max softmax section
// (depth-5 instead of serial fmax chain), one pack. sT[17][144] f32 (stride 144: gather
// banks spread via lc*143 odd-stride, <=2-way). LDS 55.5KB -> 2 blocks/CU = 8 waves/CU
// (measured effective residency was ~7 and perf was residency-invariant: R6 28% == R9 21%).
__global__ __launch_bounds__(256)
void attn_mfma_kernel(const short* __restrict__ qg, const short* __restrict__ kb,
                      const short* __restrict__ pb, const short* __restrict__ vT,
                      const float* __restrict__ ub, const float* __restrict__ vb,
                      short* __restrict__ ctxb) {
    // swizzled decode: all blocks of head h land on XCD h
    const int i0  = blockIdx.x;
    const int xcd = i0 & 7, idx = i0 >> 3;      // idx in [0,128)
    const int h   = xcd;
    const int b   = idx >> 5;
    const int w   = threadIdx.x >> 6;
    const int q0  = (idx & 31) * 64 + 16 * w;
    const int l   = threadIdx.x & 63;
    const int lc  = l & 15;
    const int lg  = l >> 4;

    __shared__ float    sT[4][17][144];     // per-wave band (window 143 cols); row 16 = boundary
    __shared__ unsigned sPk[4][2][16][32];  // per-wave P bf16-pairs; [0]=sub-a, [1]=sub-b

    const float KSC = 0.0625f * 1.44269504088896340736f;  // (1/16)*log2(e)

    // fragment setup: one q load per row + in-register bias adds, PRE-SCALED by KSC
    const size_t qrow = ((size_t)(b*L_SEQ + q0 + lc))*DMODEL + h*DHEAD + lg*8;
    const short8 qraw = *(const short8*)(qg + qrow);
    short8 qraw_sh = zero8();
    {
        const int r2 = q0 + lc + 1;
        if (r2 < L_SEQ)
            qraw_sh = *(const short8*)(qg + ((size_t)(b*L_SEQ + r2))*DMODEL + h*DHEAD + lg*8);
    }
    short8 aqu, aqv, aqv_sh;
    #pragma unroll
    for (int j = 0; j < 8; ++j) {
        const float u_ = ub[h*DHEAD + lg*8 + j];
        const float v_ = vb[h*DHEAD + lg*8 + j];
        const float f  = bf2f(qraw[j]);
        aqu[j]    = f2bf((f + u_) * KSC);
        aqv[j]    = f2bf((f + v_) * KSC);
        aqv_sh[j] = f2bf((bf2f(qraw_sh[j]) + v_) * KSC);
    }

    float m_r = -3.0e38f, l_r = 0.f;     // l_r lane-partial (reduced in epilogue)
    f32x4 acc0 = {0.f,0.f,0.f,0.f}, acc1 = {0.f,0.f,0.f,0.f};

    const short* kbase = kb + ((size_t)(b*L_SEQ))*DMODEL + h*DHEAD;
    const short* pbase = pb + h*DHEAD;
    const short* vbase = vT + ((size_t)((b*NH + h)*DHEAD))*L_SEQ;
    const f32x4 zf = {0.f, 0.f, 0.f, 0.f};

    // ptilde loader: window slot cc (0..8) at pair-base k0n; A-row jj = 16*cc + lc
    auto loadP = [&](int k0n, int cc) -> short8 {
        const int rho = (k0n - q0 - 17) + 16*cc + lc;
        if (rho == -1) return zero8();
        const int pr = rho + (rho < 0 ? (L_SEQ+1) : 0);
        return *(const short8*)(pbase + (size_t)pr*DMODEL + lg*8);
    };

    short8 kfrag[8], pfrag[9], vfrag[2][2][2];
    #pragma unroll
    for (int ct = 0; ct < 8; ++ct)
        kfrag[ct] = *(const short8*)(kbase + (size_t)(ct*16 + lc)*DMODEL + lg*8);
    #pragma unroll
    for (int cc = 0; cc < 9; ++cc) pfrag[cc] = loadP(0, cc);

    const int colc = 4*lg + 15 - lc;     // gather col = 16*cti + colc + r, cti in [0,8)
    const int swkey = lc & 7;

    for (int k0 = 0; k0 < L_SEQ; k0 += 128) {
        const int cthr = 17 - (k0 - q0);   // up = (col >= cthr); cols span [0,142]

        // ---- content: S^T tiles for both sub-tiles (A = K, B = Qu) ----
        f32x4 cts[8];
        #pragma unroll
        for (int ct = 0; ct < 8; ++ct)
            cts[ct] = __builtin_amdgcn_mfma_f32_16x16x32_bf16(kfrag[ct], aqu, zf, 0, 0, 0);

        // ---- pos band: 3-path over the PAIR ----
        if (cthr > 142) {
            #pragma unroll
            for (int cc = 0; cc < 9; ++cc) {
                f32x4 tt = __builtin_amdgcn_mfma_f32_16x16x32_bf16(pfrag[cc], aqv, zf, 0, 0, 0);
                *(f32x4*)&sT[w][lc][16*cc + 4*lg] = tt;
            }
        } else if (cthr <= 0) {
            #pragma unroll
            for (int cc = 0; cc < 9; ++cc) {
                f32x4 tt = __builtin_amdgcn_mfma_f32_16x16x32_bf16(pfrag[cc], aqv_sh, zf, 0, 0, 0);
                *(f32x4*)&sT[w][lc][16*cc + 4*lg] = tt;
            }
        } else {
            #pragma unroll
            for (int cc = 0; cc < 9; ++cc) {
                f32x4 tt = __builtin_amdgcn_mfma_f32_16x16x32_bf16(pfrag[cc], aqv, zf, 0, 0, 0);
                *(f32x4*)&sT[w][lc][16*cc + 4*lg] = tt;
                f32x4 tt2 = __builtin_amdgcn_mfma_f32_16x16x32_bf16(pfrag[cc], aqv_sh, zf, 0, 0, 0);
                if (lc == 15) *(f32x4*)&sT[w][16][16*cc + 4*lg] = tt2;
            }
        }

        // ---- rotate p-window (slide 128 = 8 slots) + prefetch next pair's K/p ----
        pfrag[0] = pfrag[8];
        if (k0 + 128 < L_SEQ) {
            #pragma unroll
            for (int ct = 0; ct < 8; ++ct)
                kfrag[ct] = *(const short8*)(kbase + (size_t)(k0 + 128 + ct*16 + lc)*DMODEL + lg*8);
            #pragma unroll
            for (int cc = 1; cc < 9; ++cc) pfrag[cc] = loadP(k0 + 128, cc);
        }

        asm volatile("s_waitcnt lgkmcnt(0)" ::: "memory");  // sT(t) + sPk(t-1) visible

        // ---- deferred PV of PREVIOUS pair (overlaps this pair's gather/softmax) ----
        if (k0) {
            #pragma unroll
            for (int st = 0; st < 2; ++st)
                #pragma unroll
                for (int kc = 0; kc < 2; ++kc) {
                    const int idx2 = ((4*kc + lg) ^ swkey) << 2;
                    const short8 bp = *(const short8*)&sPk[w][st][lc][idx2];
                    acc0 = __builtin_amdgcn_mfma_f32_16x16x32_bf16(vfrag[st][0][kc], bp, acc0, 0, 0, 0);
                    acc1 = __builtin_amdgcn_mfma_f32_16x16x32_bf16(vfrag[st][1][kc], bp, acc1, 0, 0, 0);
                }
        }
        // ---- V for CURRENT pair (consumed next iteration / epilogue) ----
        #pragma unroll
        for (int st = 0; st < 2; ++st)
            #pragma unroll
            for (int dt = 0; dt < 2; ++dt)
                #pragma unroll
                for (int kc = 0; kc < 2; ++kc)
                    vfrag[st][dt][kc] = *(const short8*)(vbase + (size_t)(16*dt + lc)*L_SEQ
                                                         + k0 + 64*st + kc*32 + lg*8);

        // ---- rel-shift gather + combine (32 elements, one batch) ----
        float sc[8][4];
        if (cthr > 142 || cthr <= 0) {
            const float* rowp = &sT[w][lc][0];
            #pragma unroll
            for (int ct = 0; ct < 8; ++ct)
                #pragma unroll
                for (int r = 0; r < 4; ++r)
                    sc[ct][r] = cts[ct][r] + rowp[16*ct + colc + r];
        } else {
            #pragma unroll
            for (int ct = 0; ct < 8; ++ct)
                #pragma unroll
                for (int r = 0; r < 4; ++r) {
                    const int col = 16*ct + colc + r;
                    const int up = (col >= cthr) ? 1 : 0;
                    sc[ct][r] = cts[ct][r] + sT[w][lc + up][col];
                }
        }

        // ---- defer-max softmax over 32 (tree-max, depth 5) ----
        float m8[8];
        #pragma unroll
        for (int ct = 0; ct < 8; ++ct)
            m8[ct] = fmaxf(fmaxf(sc[ct][0], sc[ct][1]), fmaxf(sc[ct][2], sc[ct][3]));
        float m4a = fmaxf(m8[0], m8[4]), m4b = fmaxf(m8[1], m8[5]);
        float m4c = fmaxf(m8[2], m8[6]), m4d = fmaxf(m8[3], m8[7]);
        float pmax = fmaxf(fmaxf(m4a, m4b), fmaxf(m4c, m4d));
        if (!__all(pmax - m_r <= 8.0f)) {          // rare, wave-uniform
            float mx = fmaxf(pmax, __shfl_xor(pmax, 16));
            mx = fmaxf(mx, __shfl_xor(mx, 32));
            const float mn = fmaxf(m_r, mx);
            const float alpha = exp2f(m_r - mn);
            m_r = mn;
            l_r *= alpha;
            #pragma unroll
            for (int r = 0; r < 4; ++r) { acc0[r] *= alpha; acc1[r] *= alpha; }
        }
        float ts = 0.f;
        #pragma unroll
        for (int ct = 0; ct < 8; ++ct)
            #pragma unroll
            for (int r = 0; r < 4; ++r) {
                sc[ct][r] = exp2f(sc[ct][r] - m_r);   // <= 2^8
                ts += sc[ct][r];
            }
        l_r += ts;

        // ---- pack P -> sPk[buf = cti>>2] (NO fence; drained by next iteration's fence) ----
        #pragma unroll
        for (int ct = 0; ct < 8; ++ct) {
            unsigned lo, hi;
            asm("v_cvt_pk_bf16_f32 %0, %1, %2" : "=v"(lo) : "v"(sc[ct][0]), "v"(sc[ct][1]));
            asm("v_cvt_pk_bf16_f32 %0, %1, %2" : "=v"(hi) : "v"(sc[ct][2]), "v"(sc[ct][3]));
            const int kbi = 2*(ct & 3) + (lg >> 1);
            const int idx2 = ((kbi ^ swkey) << 2) + 2*(lg & 1);
            *(uint2*)&sPk[w][ct >> 2][lc][idx2] = make_uint2(lo, hi);
        }
    }

    // ---- epilogue: final PV (last pair), reduce l_r, transpose, emit bf16 ----
    asm volatile("s_waitcnt lgkmcnt(0)" ::: "memory");
    #pragma unroll
    for (int st = 0; st < 2; ++st)
        #pragma unroll
        for (int kc = 0; kc < 2; ++kc) {
            const int idx2 = ((4*kc + lg) ^ swkey) << 2;
            const short8 bp = *(const short8*)&sPk[w][st][lc][idx2];
            acc0 = __builtin_amdgcn_mfma_f32_16x16x32_bf16(vfrag[st][0][kc], bp, acc0, 0, 0, 0);
            acc1 = __builtin_amdgcn_mfma_f32_16x16x32_bf16(vfrag[st][1][kc], bp, acc1, 0, 0, 0);
        }
    l_r += __shfl_xor(l_r, 16);
    l_r += __shfl_xor(l_r, 32);
    float* sCt = (float*)&sPk[w][0][0][0];   // [16][32] f32 view
    const float inv = 1.f / l_r;
    {
        f32x4 o0, o1;
        #pragma unroll
        for (int r = 0; r < 4; ++r) { o0[r] = acc0[r]*inv; o1[r] = acc1[r]*inv; }
        *(f32x4*)&sCt[lc*32 + 4*lg]      = o0;
        *(f32x4*)&sCt[lc*32 + 16 + 4*lg] = o1;
    }
    asm volatile("s_waitcnt lgkmcnt(0)" ::: "memory");
    const int rr = l >> 2;
    const int c0 = (l & 3) * 8;
    short8 ob;
    #pragma unroll
    for (int j = 0; j < 8; ++j) ob[j] = f2bf(sCt[rr*32 + c0 + j]);
    *(short8*)(ctxb + ((size_t)(b*L_SEQ + q0 + rr))*DMODEL + h*DHEAD + c0) = ob;
}

extern "C" void kernel_launch(void* const* d_in, const int* in_sizes, int n_in,
                              void* d_out, int out_size, void* d_ws, size_t ws_size,
                              hipStream_t stream) {
    (void)in_sizes; (void)n_in; (void)out_size; (void)ws_size;
    const float* x     = (const float*)d_in[0];
    const float* gamma = (const float*)d_in[1];
    const float* beta  = (const float*)d_in[2];
    const float* Wq    = (const float*)d_in[3];
    const float* bq    = (const float*)d_in[4];
    const float* Wk    = (const float*)d_in[5];
    const float* bk    = (const float*)d_in[6];
    const float* Wv    = (const float*)d_in[7];
    const float* bv    = (const float*)d_in[8];
    const float* Wp    = (const float*)d_in[9];
    const float* ub    = (const float*)d_in[10];
    const float* vb    = (const float*)d_in[11];
    const float* Wo    = (const float*)d_in[12];
    const float* bo    = (const float*)d_in[13];
    float* out = (float*)d_out;

    char* wsb = (char*)d_ws;
    short* ctxb = (short*)wsb;                                   // 4 MB bf16
    short* xnb  = (short*)(wsb + 4194304);                       // 4 MB bf16
    short* peb  = (short*)(wsb + 4194304 + 4194304);             // 1 MB bf16
    short* WT   = (short*)(wsb + 4194304 + 4194304 + 1048576);   // 640 KB bf16 (5 mats)
    short* q    = WT  + (size_t)5*65536;                         // 4 MB
    short* kbf  = q   + (size_t)NROW*DMODEL;                     // 4 MB
    short* vT   = kbf + (size_t)NROW*DMODEL;                     // 4 MB
    short* pbf  = vT  + (size_t)NROW*DMODEL;                     // 1 MB

    prep_kernel<<<3152, 256, 0, stream>>>(x, gamma, beta, xnb, peb,
                                          Wq, Wk, Wv, Wp, Wo, WT);
    projmm_kernel<<<416, 256, 0, stream>>>(xnb, peb, WT, bq, bk, bv, q, kbf, vT, pbf);
    attn_mfma_kernel<<<1024, 256, 0, stream>>>(q, kbf, pbf, vT, ub, vb, ctxb);
    outmm_kernel<<<128, 256, 0, stream>>>(ctxb, WT + (size_t)4*65536, bo, out);
}

// Round 15
// 240.077 us; speedup vs baseline: 1.0455x; 1.0455x over previous
//
#include <hip/hip_runtime.h>
#include <hip/hip_bf16.h>
#include <math.h>

#define L_SEQ 2048
#define NB 4
#define DMODEL 256
#define NH 8
#define DHEAD 32
#define NROW (NB*L_SEQ)

typedef __attribute__((ext_vector_type(8))) short short8;
typedef __attribute__((ext_vector_type(4))) float f32x4;

__device__ __forceinline__ float bf2f(short v) {
    union { unsigned u; float f; } x; x.u = ((unsigned)(unsigned short)v) << 16; return x.f;
}
__device__ __forceinline__ short f2bf(float f) {
    union { float f; unsigned u; } x; x.f = f;
    unsigned r = x.u + 0x7fff + ((x.u >> 16) & 1);
    return (short)(r >> 16);
}
__device__ __forceinline__ short8 zero8() {
    short8 z;
    #pragma unroll
    for (int i = 0; i < 8; ++i) z[i] = 0;
    return z;
}

// ---- fused prep: LN (0..2047) + PE (2048..3071) + wcvt (3072..3151) + pext zero row (3152) ----
__global__ __launch_bounds__(256)
void prep_kernel(const float* __restrict__ x, const float* __restrict__ gamma,
                 const float* __restrict__ beta, short* __restrict__ xnb,
                 short* __restrict__ peb,
                 const float* __restrict__ W0, const float* __restrict__ W1,
                 const float* __restrict__ W2, const float* __restrict__ W3,
                 const float* __restrict__ W4, short* __restrict__ WT,
                 short* __restrict__ pext) {
    const int bid = blockIdx.x;
    __shared__ float s[64][65];
    if (bid < 2048) {
        int lane = threadIdx.x & 63;
        int row  = bid*4 + (threadIdx.x >> 6);
        const float4 a = *(const float4*)(x + (size_t)row*DMODEL + lane*4);
        float sm  = a.x+a.y+a.z+a.w;
        float s2 = a.x*a.x+a.y*a.y+a.z*a.z+a.w*a.w;
        #pragma unroll
        for (int o = 32; o; o >>= 1) { sm += __shfl_xor(sm,o); s2 += __shfl_xor(s2,o); }
        float mu  = sm * (1.f/DMODEL);
        float var = s2 * (1.f/DMODEL) - mu*mu;
        float rst = rsqrtf(var + 1e-3f);
        const float4 g  = *(const float4*)(gamma + lane*4);
        const float4 bt = *(const float4*)(beta  + lane*4);
        short4 o;
        o.x = f2bf((a.x-mu)*rst*g.x + bt.x);
        o.y = f2bf((a.y-mu)*rst*g.y + bt.y);
        o.z = f2bf((a.z-mu)*rst*g.z + bt.z);
        o.w = f2bf((a.w-mu)*rst*g.w + bt.w);
        *(short4*)(xnb + (size_t)row*DMODEL + lane*4) = o;
    } else if (bid < 3072) {
        int idx = (bid-2048)*256 + threadIdx.x;
        int l = idx >> 7, m = idx & 127;
        double ang = (double)l * exp((double)m * (-9.210340371976184/128.0));
        unsigned sv = (unsigned)(unsigned short)f2bf((float)sin(ang));
        unsigned cv = (unsigned)(unsigned short)f2bf((float)cos(ang));
        *(unsigned*)(peb + l*DMODEL + 2*m) = sv | (cv << 16);
    } else if (bid < 3152) {
        const int r  = bid - 3072;           // 0..79
        const int z  = r >> 4, rr = r & 15;
        const float* W = (z==0)?W0:(z==1)?W1:(z==2)?W2:(z==3)?W3:W4;
        short* O = WT + (size_t)z*65536;
        const int k0 = (rr >> 2)*64, n0 = (rr & 3)*64;
        const int c = threadIdx.x & 63, r4 = threadIdx.x >> 6;
        #pragma unroll
        for (int i = 0; i < 16; ++i) {
            int rw = r4 + 4*i;
            s[c][rw] = W[(size_t)(k0+rw)*256 + n0 + c];
        }
        __syncthreads();
        #pragma unroll
        for (int i = 0; i < 16; ++i) {
            int rn = r4 + 4*i;
            O[(size_t)(n0+rn)*256 + k0 + c] = f2bf(s[rn][c]);
        }
    } else {
        // zero row L_SEQ of pext (the rho == -1 row)
        if (threadIdx.x < 64) {
            short4 z4 = {0,0,0,0};
            *(short4*)(pext + (size_t)L_SEQ*DMODEL + threadIdx.x*4) = z4;
        }
    }
}

// ---------------- bf16 MFMA projections: C = A @ W (+bias) ----------------
// z==2 (V) writes DIRECTLY to vT[b,h,d,l]; z==3 (p) writes BOTH pext copies.
__global__ __launch_bounds__(256, 2)
void projmm_kernel(const short* __restrict__ xnb, const short* __restrict__ peb,
                   const short* __restrict__ WT,
                   const float* __restrict__ bq, const float* __restrict__ bk,
                   const float* __restrict__ bv,
                   short* __restrict__ q, short* __restrict__ kb,
                   short* __restrict__ vT, short* __restrict__ pext) {
    const int bid = blockIdx.x;
    int z, rb;
    if (bid < 384) { z = bid >> 7; rb = bid & 127; }
    else           { z = 3;        rb = bid - 384; }
    const short* A = (z == 3) ? peb : xnb;
    const short* W = WT + (size_t)z*65536;
    const int t = threadIdx.x;
    const int w = t >> 6, l = t & 63, lc = l & 15, lg = l >> 4;
    const int m0 = rb*64 + 16*w;

    short8 afr[8];
    #pragma unroll
    for (int ks = 0; ks < 8; ++ks)
        afr[ks] = *(const short8*)(A + (size_t)(m0+lc)*256 + ks*32 + lg*8);

    const f32x4 zf = {0.f,0.f,0.f,0.f};
    f32x4 acc[16];
    #pragma unroll
    for (int ct = 0; ct < 16; ++ct) acc[ct] = zf;

    #pragma unroll
    for (int ct = 0; ct < 16; ++ct) {
        #pragma unroll
        for (int ks = 0; ks < 8; ++ks) {
            const short8 bfr = *(const short8*)(W + (size_t)(ct*16+lc)*256 + ks*32 + lg*8);
            acc[ct] = __builtin_amdgcn_mfma_f32_16x16x32_bf16(afr[ks], bfr, acc[ct], 0, 0, 0);
        }
    }

    if (z == 2) {
        const int bb = m0 >> 11;
        const int l0 = (m0 & 2047) + 4*lg;
        #pragma unroll
        for (int ct = 0; ct < 16; ++ct) {
            const int cc = ct*16 + lc;
            const float bias = bv[cc];
            const int hh = cc >> 5, dd = cc & 31;
            short4 o;
            o.x = f2bf(acc[ct][0] + bias);
            o.y = f2bf(acc[ct][1] + bias);
            o.z = f2bf(acc[ct][2] + bias);
            o.w = f2bf(acc[ct][3] + bias);
            *(short4*)(vT + ((size_t)((bb*NH + hh)*DHEAD + dd))*L_SEQ + l0) = o;
        }
    } else if (z == 3) {
        #pragma unroll
        for (int ct = 0; ct < 16; ++ct) {
            const int cc = ct*16 + lc;
            #pragma unroll
            for (int r = 0; r < 4; ++r) {
                const int rr = m0 + 4*lg + r;
                const short v = f2bf(acc[ct][r]);
                pext[(size_t)rr*DMODEL + cc] = v;
                pext[(size_t)(rr + L_SEQ + 1)*DMODEL + cc] = v;
            }
        }
    } else {
        #pragma unroll
        for (int ct = 0; ct < 16; ++ct) {
            const int cc = ct*16 + lc;
            const float bias = (z == 0) ? bq[cc] : bk[cc];
            #pragma unroll
            for (int r = 0; r < 4; ++r) {
                const size_t idx = (size_t)(m0 + 4*lg + r)*DMODEL + cc;
                const short v = f2bf(acc[ct][r] + bias);
                if (z == 0) q[idx] = v;
                else        kb[idx] = v;
            }
        }
    }
}

// ---------------- bf16 MFMA out-projection: out = ctxb @ Wo + bo (f32 out) ----------------
__global__ __launch_bounds__(256, 2)
void outmm_kernel(const short* __restrict__ ctxb, const short* __restrict__ WTo,
                  const float* __restrict__ bo, float* __restrict__ out) {
    const int rb = blockIdx.x;
    const int t = threadIdx.x;
    const int w = t >> 6, l = t & 63, lc = l & 15, lg = l >> 4;
    const int m0 = rb*64 + 16*w;

    short8 afr[8];
    #pragma unroll
    for (int ks = 0; ks < 8; ++ks)
        afr[ks] = *(const short8*)(ctxb + (size_t)(m0+lc)*256 + ks*32 + lg*8);

    const f32x4 zf = {0.f,0.f,0.f,0.f};
    f32x4 acc[16];
    #pragma unroll
    for (int ct = 0; ct < 16; ++ct) acc[ct] = zf;

    #pragma unroll
    for (int ct = 0; ct < 16; ++ct) {
        #pragma unroll
        for (int ks = 0; ks < 8; ++ks) {
            const short8 bfr = *(const short8*)(WTo + (size_t)(ct*16+lc)*256 + ks*32 + lg*8);
            acc[ct] = __builtin_amdgcn_mfma_f32_16x16x32_bf16(afr[ks], bfr, acc[ct], 0, 0, 0);
        }
    }

    #pragma unroll
    for (int ct = 0; ct < 16; ++ct) {
        const int cc = ct*16 + lc;
        const float bias = bo[cc];
        #pragma unroll
        for (int r = 0; r < 4; ++r)
            out[(size_t)(m0 + 4*lg + r)*DMODEL + cc] = acc[ct][r] + bias;
    }
}

// ---------------- fused MFMA attention: VALU-stripped hot loop, barrier-free ----------------
// R14 bug fixed: on UNIFORM tiles the reader always uses row lc (gb0) — the 3-path pos
// band writes the needed set (unshifted OR shifted) AT rows lc. gb1 (row lc+1) is only
// for the crossing-tile up=1 case, where rows hold the unshifted set. Rest identical to
// R14: pext = [p; 0; p] (no wrap conditionals), loop-carried strided pointers, precomputed
// gather bases. Structure = R12 (KBLK=64, 3-path pos band, deferred PV, 1 fence/tile).
__global__ __launch_bounds__(256)
void attn_mfma_kernel(const short* __restrict__ qg, const short* __restrict__ kb,
                      const short* __restrict__ pext, const short* __restrict__ vT,
                      const float* __restrict__ ub, const float* __restrict__ vb,
                      short* __restrict__ ctxb) {
    const int i0  = blockIdx.x;
    const int xcd = i0 & 7, idx = i0 >> 3;      // idx in [0,128)
    const int h   = xcd;
    const int b   = idx >> 5;
    const int w   = threadIdx.x >> 6;
    const int q0  = (idx & 31) * 64 + 16 * w;
    const int l   = threadIdx.x & 63;
    const int lc  = l & 15;
    const int lg  = l >> 4;

    __shared__ float    sT[4][17][84];      // per-wave band; row 16 = crossing boundary
    __shared__ unsigned sPk[4][2][16][32];  // per-wave P bf16-pairs, double-buffered

    const float KSC = 0.0625f * 1.44269504088896340736f;  // (1/16)*log2(e)

    // fragment setup: one q load per row + in-register bias adds, PRE-SCALED by KSC
    const size_t qrow = ((size_t)(b*L_SEQ + q0 + lc))*DMODEL + h*DHEAD + lg*8;
    const short8 qraw = *(const short8*)(qg + qrow);
    short8 qraw_sh = zero8();
    {
        const int r2 = q0 + lc + 1;
        if (r2 < L_SEQ)
            qraw_sh = *(const short8*)(qg + ((size_t)(b*L_SEQ + r2))*DMODEL + h*DHEAD + lg*8);
    }
    short8 aqu, aqv, aqv_sh;
    #pragma unroll
    for (int j = 0; j < 8; ++j) {
        const float u_ = ub[h*DHEAD + lg*8 + j];
        const float v_ = vb[h*DHEAD + lg*8 + j];
        const float f  = bf2f(qraw[j]);
        aqu[j]    = f2bf((f + u_) * KSC);
        aqv[j]    = f2bf((f + v_) * KSC);
        aqv_sh[j] = f2bf((bf2f(qraw_sh[j]) + v_) * KSC);
    }

    float m_r = -3.0e38f, l_r = 0.f;     // l_r lane-partial (reduced in epilogue)
    f32x4 acc0 = {0.f,0.f,0.f,0.f}, acc1 = {0.f,0.f,0.f,0.f};
    const f32x4 zf = {0.f, 0.f, 0.f, 0.f};

    // loop-carried load pointers (uniform part advances by constant; lane part constant)
    const short* kfetch = kb + ((size_t)(b*L_SEQ) + lc)*DMODEL + h*DHEAD + lg*8;
    const short* pcur   = pext + ((size_t)(L_SEQ - 16 - q0 + lc))*DMODEL + h*DHEAD + lg*8;
    const short* vcur   = vT + ((size_t)((b*NH + h)*DHEAD + lc))*L_SEQ + lg*8;

    // persistent fragments
    short8 kfrag[4], pfrag[5], vfrag[2][2];
    #pragma unroll
    for (int ct = 0; ct < 4; ++ct)
        kfrag[ct] = *(const short8*)(kfetch + (size_t)ct*16*DMODEL);
    #pragma unroll
    for (int cc = 0; cc < 5; ++cc)
        pfrag[cc] = *(const short8*)(pcur + (size_t)cc*16*DMODEL);
    kfetch += (size_t)64*DMODEL;

    const int colc = 4*lg + 15 - lc;
    // precomputed gather bases (lane-constant)
    const float* gb0 = &sT[w][lc][colc];
    const float* gb1 = &sT[w][lc+1][colc];
    const int swkey = lc & 7;

    for (int k0 = 0; k0 < L_SEQ; k0 += 64) {
        const int cthr = 17 - (k0 - q0);   // up = (col >= cthr), cols in [0,78]
        const int tbuf = (k0 >> 6) & 1;

        // ---- content: S^T tiles (A = K, B = Qu) ----
        f32x4 cts[4];
        #pragma unroll
        for (int ct = 0; ct < 4; ++ct)
            cts[ct] = __builtin_amdgcn_mfma_f32_16x16x32_bf16(kfrag[ct], aqu, zf, 0, 0, 0);

        // ---- pos band: 3-path (wave-uniform cthr) ----
        if (cthr > 78) {
            #pragma unroll
            for (int cc = 0; cc < 5; ++cc) {
                f32x4 tt = __builtin_amdgcn_mfma_f32_16x16x32_bf16(pfrag[cc], aqv, zf, 0, 0, 0);
                *(f32x4*)&sT[w][lc][16*cc + 4*lg] = tt;
            }
        } else if (cthr <= 0) {
            #pragma unroll
            for (int cc = 0; cc < 5; ++cc) {
                f32x4 tt = __builtin_amdgcn_mfma_f32_16x16x32_bf16(pfrag[cc], aqv_sh, zf, 0, 0, 0);
                *(f32x4*)&sT[w][lc][16*cc + 4*lg] = tt;
            }
        } else {
            #pragma unroll
            for (int cc = 0; cc < 5; ++cc) {
                f32x4 tt = __builtin_amdgcn_mfma_f32_16x16x32_bf16(pfrag[cc], aqv, zf, 0, 0, 0);
                *(f32x4*)&sT[w][lc][16*cc + 4*lg] = tt;
                f32x4 tt2 = __builtin_amdgcn_mfma_f32_16x16x32_bf16(pfrag[cc], aqv_sh, zf, 0, 0, 0);
                if (lc == 15) *(f32x4*)&sT[w][16][16*cc + 4*lg] = tt2;
            }
        }

        // ---- rotate p-window + prefetch next tile's K/p (strided pointers) ----
        pfrag[0] = pfrag[4];
        if (k0 + 64 < L_SEQ) {
            #pragma unroll
            for (int ct = 0; ct < 4; ++ct)
                kfrag[ct] = *(const short8*)(kfetch + (size_t)ct*16*DMODEL);
            #pragma unroll
            for (int cc = 1; cc < 5; ++cc)
                pfrag[cc] = *(const short8*)(pcur + (size_t)(64 + 16*cc)*DMODEL);
        }
        kfetch += (size_t)64*DMODEL;
        pcur   += (size_t)64*DMODEL;

        asm volatile("s_waitcnt lgkmcnt(0)" ::: "memory");  // sT(t) + sPk(t-1) visible

        // ---- deferred PV of PREVIOUS tile ----
        if (k0) {
            #pragma unroll
            for (int kc = 0; kc < 2; ++kc) {
                const int idx2 = ((4*kc + lg) ^ swkey) << 2;
                const short8 bp = *(const short8*)&sPk[w][tbuf ^ 1][lc][idx2];
                acc0 = __builtin_amdgcn_mfma_f32_16x16x32_bf16(vfrag[0][kc], bp, acc0, 0, 0, 0);
                acc1 = __builtin_amdgcn_mfma_f32_16x16x32_bf16(vfrag[1][kc], bp, acc1, 0, 0, 0);
            }
        }
        // ---- V for CURRENT tile (strided pointer) ----
        #pragma unroll
        for (int dt = 0; dt < 2; ++dt)
            #pragma unroll
            for (int kc = 0; kc < 2; ++kc)
                vfrag[dt][kc] = *(const short8*)(vcur + (size_t)dt*16*L_SEQ + kc*32);
        vcur += 64;

        // ---- rel-shift gather + combine (constant-immediate reads) ----
        // UNIFORM tiles: needed set (unshifted or shifted) is written AT rows lc -> gb0.
        float sc[4][4];
        if (cthr > 78 || cthr <= 0) {
            #pragma unroll
            for (int ct = 0; ct < 4; ++ct)
                #pragma unroll
                for (int r = 0; r < 4; ++r)
                    sc[ct][r] = cts[ct][r] + gb0[16*ct + r];
        } else {
            #pragma unroll
            for (int ct = 0; ct < 4; ++ct)
                #pragma unroll
                for (int r = 0; r < 4; ++r) {
                    const bool up = (16*ct + colc + r) >= cthr;
                    sc[ct][r] = cts[ct][r] + (up ? gb1 : gb0)[16*ct + r];
                }
        }

        // ---- defer-max softmax ----
        float pmax = sc[0][0];
        #pragma unroll
        for (int ct = 0; ct < 4; ++ct)
            #pragma unroll
            for (int r = 0; r < 4; ++r) pmax = fmaxf(pmax, sc[ct][r]);
        if (!__all(pmax - m_r <= 8.0f)) {          // rare, wave-uniform
            float mx = fmaxf(pmax, __shfl_xor(pmax, 16));
            mx = fmaxf(mx, __shfl_xor(mx, 32));
            const float mn = fmaxf(m_r, mx);
            const float alpha = exp2f(m_r - mn);
            m_r = mn;
            l_r *= alpha;
            #pragma unroll
            for (int r = 0; r < 4; ++r) { acc0[r] *= alpha; acc1[r] *= alpha; }
        }
        float ts = 0.f;
        #pragma unroll
        for (int ct = 0; ct < 4; ++ct)
            #pragma unroll
            for (int r = 0; r < 4; ++r) {
                sc[ct][r] = exp2f(sc[ct][r] - m_r);   // <= 2^8
                ts += sc[ct][r];
            }
        l_r += ts;

        // ---- pack P -> sPk[tbuf] (no fence; drained by next tile's fence) ----
        #pragma unroll
        for (int ct = 0; ct < 4; ++ct) {
            unsigned lo, hi;
            asm("v_cvt_pk_bf16_f32 %0, %1, %2" : "=v"(lo) : "v"(sc[ct][0]), "v"(sc[ct][1]));
            asm("v_cvt_pk_bf16_f32 %0, %1, %2" : "=v"(hi) : "v"(sc[ct][2]), "v"(sc[ct][3]));
            const int kbi = 2*ct + (lg >> 1);
            const int idx2 = ((kbi ^ swkey) << 2) + 2*(lg & 1);
            *(uint2*)&sPk[w][tbuf][lc][idx2] = make_uint2(lo, hi);
        }
    }

    // ---- epilogue: final PV (buffer 1), reduce l_r, transpose, emit bf16 ----
    asm volatile("s_waitcnt lgkmcnt(0)" ::: "memory");
    #pragma unroll
    for (int kc = 0; kc < 2; ++kc) {
        const int idx2 = ((4*kc + lg) ^ swkey) << 2;
        const short8 bp = *(const short8*)&sPk[w][1][lc][idx2];
        acc0 = __builtin_amdgcn_mfma_f32_16x16x32_bf16(vfrag[0][kc], bp, acc0, 0, 0, 0);
        acc1 = __builtin_amdgcn_mfma_f32_16x16x32_bf16(vfrag[1][kc], bp, acc1, 0, 0, 0);
    }
    l_r += __shfl_xor(l_r, 16);
    l_r += __shfl_xor(l_r, 32);
    float* sCt = (float*)&sPk[w][0][0][0];
    const float inv = 1.f / l_r;
    {
        f32x4 o0, o1;
        #pragma unroll
        for (int r = 0; r < 4; ++r) { o0[r] = acc0[r]*inv; o1[r] = acc1[r]*inv; }
        *(f32x4*)&sCt[lc*32 + 4*lg]      = o0;
        *(f32x4*)&sCt[lc*32 + 16 + 4*lg] = o1;
    }
    asm volatile("s_waitcnt lgkmcnt(0)" ::: "memory");
    const int rr = l >> 2;
    const int c0 = (l & 3) * 8;
    short8 ob;
    #pragma unroll
    for (int j = 0; j < 8; ++j) ob[j] = f2bf(sCt[rr*32 + c0 + j]);
    *(short8*)(ctxb + ((size_t)(b*L_SEQ + q0 + rr))*DMODEL + h*DHEAD + c0) = ob;
}

extern "C" void kernel_launch(void* const* d_in, const int* in_sizes, int n_in,
                              void* d_out, int out_size, void* d_ws, size_t ws_size,
                              hipStream_t stream) {
    (void)in_sizes; (void)n_in; (void)out_size; (void)ws_size;
    const float* x     = (const float*)d_in[0];
    const float* gamma = (const float*)d_in[1];
    const float* beta  = (const float*)d_in[2];
    const float* Wq    = (const float*)d_in[3];
    const float* bq    = (const float*)d_in[4];
    const float* Wk    = (const float*)d_in[5];
    const float* bk    = (const float*)d_in[6];
    const float* Wv    = (const float*)d_in[7];
    const float* bv    = (const float*)d_in[8];
    const float* Wp    = (const float*)d_in[9];
    const float* ub    = (const float*)d_in[10];
    const float* vb    = (const float*)d_in[11];
    const float* Wo    = (const float*)d_in[12];
    const float* bo    = (const float*)d_in[13];
    float* out = (float*)d_out;

    char* wsb = (char*)d_ws;
    short* ctxb = (short*)wsb;                                   // 4 MB bf16
    short* xnb  = (short*)(wsb + 4194304);                       // 4 MB bf16
    short* peb  = (short*)(wsb + 4194304 + 4194304);             // 1 MB bf16
    short* WT   = (short*)(wsb + 4194304 + 4194304 + 1048576);   // 640 KB bf16 (5 mats)
    short* q    = WT  + (size_t)5*65536;                         // 4 MB
    short* kbf  = q   + (size_t)NROW*DMODEL;                     // 4 MB
    short* vT   = kbf + (size_t)NROW*DMODEL;                     // 4 MB
    short* pext = vT  + (size_t)NROW*DMODEL;                     // (2L+1)*256 bf16 ~ 2.1 MB

    prep_kernel<<<3153, 256, 0, stream>>>(x, gamma, beta, xnb, peb,
                                          Wq, Wk, Wv, Wp, Wo, WT, pext);
    projmm_kernel<<<416, 256, 0, stream>>>(xnb, peb, WT, bq, bk, bv, q, kbf, vT, pext);
    attn_mfma_kernel<<<1024, 256, 0, stream>>>(q, kbf, pext, vT, ub, vb, ctxb);
    outmm_kernel<<<128, 256, 0, stream>>>(ctxb, WT + (size_t)4*65536, bo, out);
}

// Round 16
// 160.336 us; speedup vs baseline: 1.5655x; 1.4973x over previous
//
#include <hip/hip_runtime.h>
#include <hip/hip_bf16.h>
#include <math.h>

#define L_SEQ 2048
#define NB 4
#define DMODEL 256
#define NH 8
#define DHEAD 32
#define NROW (NB*L_SEQ)

typedef __attribute__((ext_vector_type(8))) short short8;
typedef __attribute__((ext_vector_type(4))) float f32x4;

__device__ __forceinline__ float bf2f(short v) {
    union { unsigned u; float f; } x; x.u = ((unsigned)(unsigned short)v) << 16; return x.f;
}
__device__ __forceinline__ short f2bf(float f) {
    union { float f; unsigned u; } x; x.f = f;
    unsigned r = x.u + 0x7fff + ((x.u >> 16) & 1);
    return (short)(r >> 16);
}
__device__ __forceinline__ short8 zero8() {
    short8 z;
    #pragma unroll
    for (int i = 0; i < 8; ++i) z[i] = 0;
    return z;
}

// ---- fused prep: LN (0..2047) + PE (2048..3071) + wcvt (3072..3151) + pext zero row (3152) ----
__global__ __launch_bounds__(256)
void prep_kernel(const float* __restrict__ x, const float* __restrict__ gamma,
                 const float* __restrict__ beta, short* __restrict__ xnb,
                 short* __restrict__ peb,
                 const float* __restrict__ W0, const float* __restrict__ W1,
                 const float* __restrict__ W2, const float* __restrict__ W3,
                 const float* __restrict__ W4, short* __restrict__ WT,
                 short* __restrict__ pext) {
    const int bid = blockIdx.x;
    __shared__ float s[64][65];
    if (bid < 2048) {
        int lane = threadIdx.x & 63;
        int row  = bid*4 + (threadIdx.x >> 6);
        const float4 a = *(const float4*)(x + (size_t)row*DMODEL + lane*4);
        float sm  = a.x+a.y+a.z+a.w;
        float s2 = a.x*a.x+a.y*a.y+a.z*a.z+a.w*a.w;
        #pragma unroll
        for (int o = 32; o; o >>= 1) { sm += __shfl_xor(sm,o); s2 += __shfl_xor(s2,o); }
        float mu  = sm * (1.f/DMODEL);
        float var = s2 * (1.f/DMODEL) - mu*mu;
        float rst = rsqrtf(var + 1e-3f);
        const float4 g  = *(const float4*)(gamma + lane*4);
        const float4 bt = *(const float4*)(beta  + lane*4);
        short4 o;
        o.x = f2bf((a.x-mu)*rst*g.x + bt.x);
        o.y = f2bf((a.y-mu)*rst*g.y + bt.y);
        o.z = f2bf((a.z-mu)*rst*g.z + bt.z);
        o.w = f2bf((a.w-mu)*rst*g.w + bt.w);
        *(short4*)(xnb + (size_t)row*DMODEL + lane*4) = o;
    } else if (bid < 3072) {
        int idx = (bid-2048)*256 + threadIdx.x;
        int l = idx >> 7, m = idx & 127;
        double ang = (double)l * exp((double)m * (-9.210340371976184/128.0));
        unsigned sv = (unsigned)(unsigned short)f2bf((float)sin(ang));
        unsigned cv = (unsigned)(unsigned short)f2bf((float)cos(ang));
        *(unsigned*)(peb + l*DMODEL + 2*m) = sv | (cv << 16);
    } else if (bid < 3152) {
        const int r  = bid - 3072;           // 0..79
        const int z  = r >> 4, rr = r & 15;
        const float* W = (z==0)?W0:(z==1)?W1:(z==2)?W2:(z==3)?W3:W4;
        short* O = WT + (size_t)z*65536;
        const int k0 = (rr >> 2)*64, n0 = (rr & 3)*64;
        const int c = threadIdx.x & 63, r4 = threadIdx.x >> 6;
        #pragma unroll
        for (int i = 0; i < 16; ++i) {
            int rw = r4 + 4*i;
            s[c][rw] = W[(size_t)(k0+rw)*256 + n0 + c];
        }
        __syncthreads();
        #pragma unroll
        for (int i = 0; i < 16; ++i) {
            int rn = r4 + 4*i;
            O[(size_t)(n0+rn)*256 + k0 + c] = f2bf(s[rn][c]);
        }
    } else {
        if (threadIdx.x < 64) {
            short4 z4 = {0,0,0,0};
            *(short4*)(pext + (size_t)L_SEQ*DMODEL + threadIdx.x*4) = z4;
        }
    }
}

// ---------------- bf16 MFMA projections: C = A @ W (+bias) ----------------
// z==2 (V) writes DIRECTLY to vT[b,h,d,l]; z==3 (p) writes BOTH pext copies.
__global__ __launch_bounds__(256, 2)
void projmm_kernel(const short* __restrict__ xnb, const short* __restrict__ peb,
                   const short* __restrict__ WT,
                   const float* __restrict__ bq, const float* __restrict__ bk,
                   const float* __restrict__ bv,
                   short* __restrict__ q, short* __restrict__ kb,
                   short* __restrict__ vT, short* __restrict__ pext) {
    const int bid = blockIdx.x;
    int z, rb;
    if (bid < 384) { z = bid >> 7; rb = bid & 127; }
    else           { z = 3;        rb = bid - 384; }
    const short* A = (z == 3) ? peb : xnb;
    const short* W = WT + (size_t)z*65536;
    const int t = threadIdx.x;
    const int w = t >> 6, l = t & 63, lc = l & 15, lg = l >> 4;
    const int m0 = rb*64 + 16*w;

    short8 afr[8];
    #pragma unroll
    for (int ks = 0; ks < 8; ++ks)
        afr[ks] = *(const short8*)(A + (size_t)(m0+lc)*256 + ks*32 + lg*8);

    const f32x4 zf = {0.f,0.f,0.f,0.f};
    f32x4 acc[16];
    #pragma unroll
    for (int ct = 0; ct < 16; ++ct) acc[ct] = zf;

    #pragma unroll
    for (int ct = 0; ct < 16; ++ct) {
        #pragma unroll
        for (int ks = 0; ks < 8; ++ks) {
            const short8 bfr = *(const short8*)(W + (size_t)(ct*16+lc)*256 + ks*32 + lg*8);
            acc[ct] = __builtin_amdgcn_mfma_f32_16x16x32_bf16(afr[ks], bfr, acc[ct], 0, 0, 0);
        }
    }

    if (z == 2) {
        const int bb = m0 >> 11;
        const int l0 = (m0 & 2047) + 4*lg;
        #pragma unroll
        for (int ct = 0; ct < 16; ++ct) {
            const int cc = ct*16 + lc;
            const float bias = bv[cc];
            const int hh = cc >> 5, dd = cc & 31;
            short4 o;
            o.x = f2bf(acc[ct][0] + bias);
            o.y = f2bf(acc[ct][1] + bias);
            o.z = f2bf(acc[ct][2] + bias);
            o.w = f2bf(acc[ct][3] + bias);
            *(short4*)(vT + ((size_t)((bb*NH + hh)*DHEAD + dd))*L_SEQ + l0) = o;
        }
    } else if (z == 3) {
        #pragma unroll
        for (int ct = 0; ct < 16; ++ct) {
            const int cc = ct*16 + lc;
            #pragma unroll
            for (int r = 0; r < 4; ++r) {
                const int rr = m0 + 4*lg + r;
                const short v = f2bf(acc[ct][r]);
                pext[(size_t)rr*DMODEL + cc] = v;
                pext[(size_t)(rr + L_SEQ + 1)*DMODEL + cc] = v;
            }
        }
    } else {
        #pragma unroll
        for (int ct = 0; ct < 16; ++ct) {
            const int cc = ct*16 + lc;
            const float bias = (z == 0) ? bq[cc] : bk[cc];
            #pragma unroll
            for (int r = 0; r < 4; ++r) {
                const size_t idx = (size_t)(m0 + 4*lg + r)*DMODEL + cc;
                const short v = f2bf(acc[ct][r] + bias);
                if (z == 0) q[idx] = v;
                else        kb[idx] = v;
            }
        }
    }
}

// ---------------- bf16 MFMA out-projection: out = ctxb @ Wo + bo (f32 out) ----------------
__global__ __launch_bounds__(256, 2)
void outmm_kernel(const short* __restrict__ ctxb, const short* __restrict__ WTo,
                  const float* __restrict__ bo, float* __restrict__ out) {
    const int rb = blockIdx.x;
    const int t = threadIdx.x;
    const int w = t >> 6, l = t & 63, lc = l & 15, lg = l >> 4;
    const int m0 = rb*64 + 16*w;

    short8 afr[8];
    #pragma unroll
    for (int ks = 0; ks < 8; ++ks)
        afr[ks] = *(const short8*)(ctxb + (size_t)(m0+lc)*256 + ks*32 + lg*8);

    const f32x4 zf = {0.f,0.f,0.f,0.f};
    f32x4 acc[16];
    #pragma unroll
    for (int ct = 0; ct < 16; ++ct) acc[ct] = zf;

    #pragma unroll
    for (int ct = 0; ct < 16; ++ct) {
        #pragma unroll
        for (int ks = 0; ks < 8; ++ks) {
            const short8 bfr = *(const short8*)(WTo + (size_t)(ct*16+lc)*256 + ks*32 + lg*8);
            acc[ct] = __builtin_amdgcn_mfma_f32_16x16x32_bf16(afr[ks], bfr, acc[ct], 0, 0, 0);
        }
    }

    #pragma unroll
    for (int ct = 0; ct < 16; ++ct) {
        const int cc = ct*16 + lc;
        const float bias = bo[cc];
        #pragma unroll
        for (int r = 0; r < 4; ++r)
            out[(size_t)(m0 + 4*lg + r)*DMODEL + cc] = acc[ct][r] + bias;
    }
}

// ---------------- fused MFMA attention: 32 q-rows/wave (2 fused 16-row pipelines) ----------------
// R15 = null #5; effective TF sits at the documented m185 "independent-wave 16x16" plateau
// (~170 TF), broken in learn_hip by amortizing loads over more per-wave work. Here each
// wave runs TWO 16-row pipelines sharing kfrag (content A-operand loaded once), a 6-slot
// p-window (g1's slots = g0's shifted by one), and vfrag (PV A-operand). Wave-iterations
// halve (131K -> 65K); loads/iter 24 -> 14; still ONE lgkmcnt(0) fence per iteration.
// Grid 512 x 4 waves = 2 blocks/CU (77KB LDS), occupancy-insensitive per R9/R10.
__global__ __launch_bounds__(256)
void attn_mfma_kernel(const short* __restrict__ qg, const short* __restrict__ kb,
                      const short* __restrict__ pext, const short* __restrict__ vT,
                      const float* __restrict__ ub, const float* __restrict__ vb,
                      short* __restrict__ ctxb) {
    const int i0  = blockIdx.x;
    const int xcd = i0 & 7, idx = i0 >> 3;      // idx in [0,64)
    const int h   = xcd;
    const int b   = idx >> 4;
    const int w   = threadIdx.x >> 6;
    const int q0  = (idx & 15) * 128 + 32 * w;  // wave owns rows [q0, q0+32)
    const int l   = threadIdx.x & 63;
    const int lc  = l & 15;
    const int lg  = l >> 4;

    __shared__ float    sT[4][2][17][84];      // per-wave, per-group band; row 16 = boundary
    __shared__ unsigned sPk[4][2][2][16][32];  // per-wave, per-group, double-buffered P

    const float KSC = 0.0625f * 1.44269504088896340736f;  // (1/16)*log2(e)

    // fragment setup per group: rows q0+16g+lc (+1 for shifted), biases in-reg, pre-scaled
    short8 aqu[2], aqv[2], aqv_sh[2];
    #pragma unroll
    for (int g = 0; g < 2; ++g) {
        const int r1 = q0 + 16*g + lc;
        const short8 qraw = *(const short8*)(qg + ((size_t)(b*L_SEQ + r1))*DMODEL + h*DHEAD + lg*8);
        short8 qraw_sh = zero8();
        if (r1 + 1 < L_SEQ)
            qraw_sh = *(const short8*)(qg + ((size_t)(b*L_SEQ + r1 + 1))*DMODEL + h*DHEAD + lg*8);
        #pragma unroll
        for (int j = 0; j < 8; ++j) {
            const float u_ = ub[h*DHEAD + lg*8 + j];
            const float v_ = vb[h*DHEAD + lg*8 + j];
            const float f  = bf2f(qraw[j]);
            aqu[g][j]    = f2bf((f + u_) * KSC);
            aqv[g][j]    = f2bf((f + v_) * KSC);
            aqv_sh[g][j] = f2bf((bf2f(qraw_sh[j]) + v_) * KSC);
        }
    }

    float m_r[2] = {-3.0e38f, -3.0e38f}, l_r[2] = {0.f, 0.f};
    f32x4 acc[2][2];
    #pragma unroll
    for (int g = 0; g < 2; ++g)
        #pragma unroll
        for (int dt = 0; dt < 2; ++dt)
            acc[g][dt] = (f32x4){0.f,0.f,0.f,0.f};
    const f32x4 zf = {0.f, 0.f, 0.f, 0.f};

    // loop-carried pointers. pcur is GROUP-1 based: slot s => rho_g1 = (k0-q0-33)+16s+lc;
    // group 0 uses slots s=cc+1, group 1 uses s=cc (cc = 0..4 window tiles).
    const short* kfetch = kb + ((size_t)(b*L_SEQ) + lc)*DMODEL + h*DHEAD + lg*8;
    const short* pcur   = pext + ((size_t)(L_SEQ - 32 - q0 + lc))*DMODEL + h*DHEAD + lg*8;
    const short* vcur   = vT + ((size_t)((b*NH + h)*DHEAD + lc))*L_SEQ + lg*8;

    short8 kfrag[4], pfrag[6], vfrag[2][2];
    #pragma unroll
    for (int ct = 0; ct < 4; ++ct)
        kfrag[ct] = *(const short8*)(kfetch + (size_t)ct*16*DMODEL);
    #pragma unroll
    for (int s = 0; s < 6; ++s)
        pfrag[s] = *(const short8*)(pcur + (size_t)s*16*DMODEL);
    kfetch += (size_t)64*DMODEL;

    const int colc = 4*lg + 15 - lc;
    const float* gb0[2] = { &sT[w][0][lc][colc],   &sT[w][1][lc][colc]   };
    const float* gb1[2] = { &sT[w][0][lc+1][colc], &sT[w][1][lc+1][colc] };
    const int swkey = lc & 7;

    for (int k0 = 0; k0 < L_SEQ; k0 += 64) {
        const int diff = k0 - q0;
        const int tbuf = (k0 >> 6) & 1;

        // ---- content: S^T tiles, kfrag shared across both groups ----
        f32x4 cts[2][4];
        #pragma unroll
        for (int ct = 0; ct < 4; ++ct) {
            cts[0][ct] = __builtin_amdgcn_mfma_f32_16x16x32_bf16(kfrag[ct], aqu[0], zf, 0, 0, 0);
            cts[1][ct] = __builtin_amdgcn_mfma_f32_16x16x32_bf16(kfrag[ct], aqu[1], zf, 0, 0, 0);
        }

        // ---- pos band per group: 3-path; group g uses pfrag slots cc + (1-g) ----
        #pragma unroll
        for (int g = 0; g < 2; ++g) {
            const int cthr = 17 - diff + 16*g;
            const int sb = 1 - g;
            if (cthr > 78) {
                #pragma unroll
                for (int cc = 0; cc < 5; ++cc) {
                    f32x4 tt = __builtin_amdgcn_mfma_f32_16x16x32_bf16(pfrag[cc+sb], aqv[g], zf, 0, 0, 0);
                    *(f32x4*)&sT[w][g][lc][16*cc + 4*lg] = tt;
                }
            } else if (cthr <= 0) {
                #pragma unroll
                for (int cc = 0; cc < 5; ++cc) {
                    f32x4 tt = __builtin_amdgcn_mfma_f32_16x16x32_bf16(pfrag[cc+sb], aqv_sh[g], zf, 0, 0, 0);
                    *(f32x4*)&sT[w][g][lc][16*cc + 4*lg] = tt;
                }
            } else {
                #pragma unroll
                for (int cc = 0; cc < 5; ++cc) {
                    f32x4 tt = __builtin_amdgcn_mfma_f32_16x16x32_bf16(pfrag[cc+sb], aqv[g], zf, 0, 0, 0);
                    *(f32x4*)&sT[w][g][lc][16*cc + 4*lg] = tt;
                    f32x4 tt2 = __builtin_amdgcn_mfma_f32_16x16x32_bf16(pfrag[cc+sb], aqv_sh[g], zf, 0, 0, 0);
                    if (lc == 15) *(f32x4*)&sT[w][g][16][16*cc + 4*lg] = tt2;
                }
            }
        }

        // ---- slide p-window (64 keys = 4 slots of 6) + prefetch next K/p ----
        pfrag[0] = pfrag[4];
        pfrag[1] = pfrag[5];
        if (k0 + 64 < L_SEQ) {
            #pragma unroll
            for (int ct = 0; ct < 4; ++ct)
                kfrag[ct] = *(const short8*)(kfetch + (size_t)ct*16*DMODEL);
            #pragma unroll
            for (int s = 2; s < 6; ++s)
                pfrag[s] = *(const short8*)(pcur + (size_t)(64 + 16*s)*DMODEL);
        }
        kfetch += (size_t)64*DMODEL;
        pcur   += (size_t)64*DMODEL;

        asm volatile("s_waitcnt lgkmcnt(0)" ::: "memory");  // sT(t) + sPk(t-1) visible

        // ---- deferred PV of PREVIOUS tile (both groups; vfrag shared) ----
        if (k0) {
            #pragma unroll
            for (int kc = 0; kc < 2; ++kc) {
                const int idx2 = ((4*kc + lg) ^ swkey) << 2;
                const short8 bp0 = *(const short8*)&sPk[w][0][tbuf ^ 1][lc][idx2];
                const short8 bp1 = *(const short8*)&sPk[w][1][tbuf ^ 1][lc][idx2];
                acc[0][0] = __builtin_amdgcn_mfma_f32_16x16x32_bf16(vfrag[0][kc], bp0, acc[0][0], 0, 0, 0);
                acc[0][1] = __builtin_amdgcn_mfma_f32_16x16x32_bf16(vfrag[1][kc], bp0, acc[0][1], 0, 0, 0);
                acc[1][0] = __builtin_amdgcn_mfma_f32_16x16x32_bf16(vfrag[0][kc], bp1, acc[1][0], 0, 0, 0);
                acc[1][1] = __builtin_amdgcn_mfma_f32_16x16x32_bf16(vfrag[1][kc], bp1, acc[1][1], 0, 0, 0);
            }
        }
        // ---- V for CURRENT tile ----
        #pragma unroll
        for (int dt = 0; dt < 2; ++dt)
            #pragma unroll
            for (int kc = 0; kc < 2; ++kc)
                vfrag[dt][kc] = *(const short8*)(vcur + (size_t)dt*16*L_SEQ + kc*32);
        vcur += 64;

        // ---- gather + combine + defer-max softmax + pack, per group ----
        float sc[2][4][4];
        float pmax[2];
        #pragma unroll
        for (int g = 0; g < 2; ++g) {
            const int cthr = 17 - diff + 16*g;
            if (cthr > 78 || cthr <= 0) {
                #pragma unroll
                for (int ct = 0; ct < 4; ++ct)
                    #pragma unroll
                    for (int r = 0; r < 4; ++r)
                        sc[g][ct][r] = cts[g][ct][r] + gb0[g][16*ct + r];
            } else {
                #pragma unroll
                for (int ct = 0; ct < 4; ++ct)
                    #pragma unroll
                    for (int r = 0; r < 4; ++r) {
                        const bool up = (16*ct + colc + r) >= cthr;
                        sc[g][ct][r] = cts[g][ct][r] + (up ? gb1[g] : gb0[g])[16*ct + r];
                    }
            }
            pmax[g] = sc[g][0][0];
            #pragma unroll
            for (int ct = 0; ct < 4; ++ct)
                #pragma unroll
                for (int r = 0; r < 4; ++r) pmax[g] = fmaxf(pmax[g], sc[g][ct][r]);
        }
        if (!__all(fmaxf(pmax[0] - m_r[0], pmax[1] - m_r[1]) <= 8.0f)) {  // rare, uniform
            #pragma unroll
            for (int g = 0; g < 2; ++g) {
                float mx = fmaxf(pmax[g], __shfl_xor(pmax[g], 16));
                mx = fmaxf(mx, __shfl_xor(mx, 32));
                const float mn = fmaxf(m_r[g], mx);
                const float alpha = exp2f(m_r[g] - mn);
                m_r[g] = mn;
                l_r[g] *= alpha;
                acc[g][0][0]*=alpha; acc[g][0][1]*=alpha; acc[g][0][2]*=alpha; acc[g][0][3]*=alpha;
                acc[g][1][0]*=alpha; acc[g][1][1]*=alpha; acc[g][1][2]*=alpha; acc[g][1][3]*=alpha;
            }
        }
        #pragma unroll
        for (int g = 0; g < 2; ++g) {
            float ts = 0.f;
            #pragma unroll
            for (int ct = 0; ct < 4; ++ct)
                #pragma unroll
                for (int r = 0; r < 4; ++r) {
                    sc[g][ct][r] = exp2f(sc[g][ct][r] - m_r[g]);   // <= 2^8
                    ts += sc[g][ct][r];
                }
            l_r[g] += ts;
            #pragma unroll
            for (int ct = 0; ct < 4; ++ct) {
                unsigned lo, hi;
                asm("v_cvt_pk_bf16_f32 %0, %1, %2" : "=v"(lo) : "v"(sc[g][ct][0]), "v"(sc[g][ct][1]));
                asm("v_cvt_pk_bf16_f32 %0, %1, %2" : "=v"(hi) : "v"(sc[g][ct][2]), "v"(sc[g][ct][3]));
                const int kbi = 2*ct + (lg >> 1);
                const int idx2 = ((kbi ^ swkey) << 2) + 2*(lg & 1);
                *(uint2*)&sPk[w][g][tbuf][lc][idx2] = make_uint2(lo, hi);
            }
        }
    }

    // ---- epilogue: final PV (buffer 1), per-group reduce + transpose + emit bf16 ----
    asm volatile("s_waitcnt lgkmcnt(0)" ::: "memory");
    #pragma unroll
    for (int kc = 0; kc < 2; ++kc) {
        const int idx2 = ((4*kc + lg) ^ swkey) << 2;
        const short8 bp0 = *(const short8*)&sPk[w][0][1][lc][idx2];
        const short8 bp1 = *(const short8*)&sPk[w][1][1][lc][idx2];
        acc[0][0] = __builtin_amdgcn_mfma_f32_16x16x32_bf16(vfrag[0][kc], bp0, acc[0][0], 0, 0, 0);
        acc[0][1] = __builtin_amdgcn_mfma_f32_16x16x32_bf16(vfrag[1][kc], bp0, acc[0][1], 0, 0, 0);
        acc[1][0] = __builtin_amdgcn_mfma_f32_16x16x32_bf16(vfrag[0][kc], bp1, acc[1][0], 0, 0, 0);
        acc[1][1] = __builtin_amdgcn_mfma_f32_16x16x32_bf16(vfrag[1][kc], bp1, acc[1][1], 0, 0, 0);
    }
    #pragma unroll
    for (int g = 0; g < 2; ++g) {
        float lr = l_r[g];
        lr += __shfl_xor(lr, 16);
        lr += __shfl_xor(lr, 32);
        float* sCt = (float*)&sPk[w][g][0][0][0];   // [16][32] f32 view
        const float inv = 1.f / lr;
        f32x4 o0, o1;
        #pragma unroll
        for (int r = 0; r < 4; ++r) { o0[r] = acc[g][0][r]*inv; o1[r] = acc[g][1][r]*inv; }
        *(f32x4*)&sCt[lc*32 + 4*lg]      = o0;
        *(f32x4*)&sCt[lc*32 + 16 + 4*lg] = o1;
    }
    asm volatile("s_waitcnt lgkmcnt(0)" ::: "memory");
    #pragma unroll
    for (int g = 0; g < 2; ++g) {
        const float* sCt = (const float*)&sPk[w][g][0][0][0];
        const int rr = l >> 2;
        const int c0 = (l & 3) * 8;
        short8 ob;
        #pragma unroll
        for (int j = 0; j < 8; ++j) ob[j] = f2bf(sCt[rr*32 + c0 + j]);
        *(short8*)(ctxb + ((size_t)(b*L_SEQ + q0 + 16*g + rr))*DMODEL + h*DHEAD + c0) = ob;
    }
}

extern "C" void kernel_launch(void* const* d_in, const int* in_sizes, int n_in,
                              void* d_out, int out_size, void* d_ws, size_t ws_size,
                              hipStream_t stream) {
    (void)in_sizes; (void)n_in; (void)out_size; (void)ws_size;
    const float* x     = (const float*)d_in[0];
    const float* gamma = (const float*)d_in[1];
    const float* beta  = (const float*)d_in[2];
    const float* Wq    = (const float*)d_in[3];
    const float* bq    = (const float*)d_in[4];
    const float* Wk    = (const float*)d_in[5];
    const float* bk    = (const float*)d_in[6];
    const float* Wv    = (const float*)d_in[7];
    const float* bv    = (const float*)d_in[8];
    const float* Wp    = (const float*)d_in[9];
    const float* ub    = (const float*)d_in[10];
    const float* vb    = (const float*)d_in[11];
    const float* Wo    = (const float*)d_in[12];
    const float* bo    = (const float*)d_in[13];
    float* out = (float*)d_out;

    char* wsb = (char*)d_ws;
    short* ctxb = (short*)wsb;                                   // 4 MB bf16
    short* xnb  = (short*)(wsb + 4194304);                       // 4 MB bf16
    short* peb  = (short*)(wsb + 4194304 + 4194304);             // 1 MB bf16
    short* WT   = (short*)(wsb + 4194304 + 4194304 + 1048576);   // 640 KB bf16 (5 mats)
    short* q    = WT  + (size_t)5*65536;                         // 4 MB
    short* kbf  = q   + (size_t)NROW*DMODEL;                     // 4 MB
    short* vT   = kbf + (size_t)NROW*DMODEL;                     // 4 MB
    short* pext = vT  + (size_t)NROW*DMODEL;                     // (2L+1)*256 bf16 ~ 2.1 MB

    prep_kernel<<<3153, 256, 0, stream>>>(x, gamma, beta, xnb, peb,
                                          Wq, Wk, Wv, Wp, Wo, WT, pext);
    projmm_kernel<<<416, 256, 0, stream>>>(xnb, peb, WT, bq, bk, bv, q, kbf, vT, pext);
    attn_mfma_kernel<<<512, 256, 0, stream>>>(q, kbf, pext, vT, ub, vb, ctxb);
    outmm_kernel<<<128, 256, 0, stream>>>(ctxb, WT + (size_t)4*65536, bo, out);
}